// Round 1
// baseline (275.848 us; speedup 1.0000x reference)
//
#include <hip/hip_runtime.h>
#include <hip/hip_bf16.h>

typedef __hip_bfloat16 bf16;
typedef __attribute__((ext_vector_type(8))) short short8b;
typedef __attribute__((ext_vector_type(4))) short short4b;
typedef __attribute__((ext_vector_type(4))) float f32x4;

#define NAREA 2025
#define NAREA_PAD 2048

static __device__ __forceinline__ float b2f(bf16 x) { return __bfloat162float(x); }
static __device__ __forceinline__ short f2bs(float f) {
  bf16 h = __float2bfloat16(f);
  return *(short*)&h;
}

// async global->LDS, 16B/lane; lds base must be wave-uniform (lane*16 added by HW)
static __device__ __forceinline__ void gll16(const void* g, void* l) {
  __builtin_amdgcn_global_load_lds(
      (const __attribute__((address_space(1))) unsigned int*)(unsigned long long)g,
      (__attribute__((address_space(3))) unsigned int*)(unsigned int)(unsigned long long)l,
      16, 0, 0);
}

// ---------------------------------------------------------------------------
// Fused prep: [0,4800) cast x+wqkv; [4800,6528) transpose-cast wq/wk/wv;
// [6528,6536) rect table.
// ---------------------------------------------------------------------------
__global__ __launch_bounds__(256) void k_prep(
    const float* __restrict__ x, const float* __restrict__ wqkv,
    const float* __restrict__ wq, const float* __restrict__ wk,
    const float* __restrict__ wv,
    bf16* __restrict__ xb, bf16* __restrict__ wqkvb,
    bf16* __restrict__ wqT, bf16* __restrict__ wkT, bf16* __restrict__ wvT,
    int4* __restrict__ rectG, float* __restrict__ invG)
{
  __shared__ float tile[32][33];
  int b = blockIdx.x;
  if (b < 4800) {
    int idx = (b * 256 + threadIdx.x) * 4;
    const int NX = 4096 * 768;
    float4 v;
    bf16* d;
    if (idx < NX) { v = *(const float4*)(x + idx); d = xb + idx; }
    else { v = *(const float4*)(wqkv + (idx - NX)); d = wqkvb + (idx - NX); }
    short4b s = {f2bs(v.x), f2bs(v.y), f2bs(v.z), f2bs(v.w)};
    *(short4b*)d = s;
    return;
  }
  if (b < 6528) {
    int r = b - 4800;
    int z = r / 576; r -= z * 576;
    int by = r / 24, bx = r - by * 24;
    const float* src = (z == 0) ? wq : (z == 1) ? wk : wv;
    bf16* dst = (z == 0) ? wqT : (z == 1) ? wkT : wvT;
    int r0 = by * 32, c0 = bx * 32;
    int lx = threadIdx.x & 31, ly = threadIdx.x >> 5;
#pragma unroll
    for (int yy = 0; yy < 4; ++yy)
      tile[ly + yy * 8][lx] = src[(size_t)(r0 + ly + yy * 8) * 768 + c0 + lx];
    __syncthreads();
#pragma unroll
    for (int yy = 0; yy < 4; ++yy)
      dst[(size_t)(c0 + ly + yy * 8) * 768 + r0 + lx] =
          __float2bfloat16(tile[lx][ly + yy * 8]);
    return;
  }
  int m = (b - 6528) * 256 + threadIdx.x;
  if (m >= NAREA_PAD) return;
  int4 rc = make_int4(0, 0, 0, 0);
  float iv = 0.f;
  if (m < NAREA) {
    int rem = m, ah = 1, aw = 1, found = 0;
    for (int a = 1; a <= 3 && !found; ++a)
      for (int w = 1; w <= 3 && !found; ++w) {
        int np = (17 - a) * (17 - w);
        if (rem < np) { ah = a; aw = w; found = 1; }
        else rem -= np;
      }
    int cw = 17 - aw;
    int y = rem / cw, xx = rem - y * cw;
    rc.x = (y * 17 + xx) * 64;
    rc.y = (y * 17 + (xx + aw)) * 64;
    rc.z = ((y + ah) * 17 + xx) * 64;
    rc.w = ((y + ah) * 17 + (xx + aw)) * 64;
    iv = 1.0f / (float)(ah * aw);
  }
  rectG[m] = rc;
  invG[m] = iv;
}

// ---------------------------------------------------------------------------
// Transpose-cast 768x768 fp32 -> bf16 (wo; runs after attn frees Ik region)
// ---------------------------------------------------------------------------
__global__ __launch_bounds__(256) void k_tcast1(
    const float* __restrict__ src, bf16* __restrict__ dst)
{
  __shared__ float tile[32][33];
  int r0 = blockIdx.y * 32, c0 = blockIdx.x * 32;
  int lx = threadIdx.x & 31, ly = threadIdx.x >> 5;
#pragma unroll
  for (int yy = 0; yy < 4; ++yy)
    tile[ly + yy * 8][lx] = src[(size_t)(r0 + ly + yy * 8) * 768 + c0 + lx];
  __syncthreads();
#pragma unroll
  for (int yy = 0; yy < 4; ++yy)
    dst[(size_t)(c0 + ly + yy * 8) * 768 + r0 + lx] =
        __float2bfloat16(tile[lx][ly + yy * 8]);
}

// ===========================================================================
// MFMA GEMM core (BM=BN=128, BK=32, 256 thr): staging via global_load_lds
// width=16 issued AFTER the barrier into the other buffer (m97 pattern);
// the next barrier's vmcnt drain completes it. 1 barrier/K-tile.
// Dest mapping: thread tid -> as + tid*16B == wave base (w*1024B) + lane*16.
// ===========================================================================

// Wc^T[t][n][m] (bf16) = (wqkv[:,t] @ w_{q,k,v})^T
__global__ __launch_bounds__(256) void k_combine_m(
    const bf16* __restrict__ wqkvb, const bf16* __restrict__ wqT,
    const bf16* __restrict__ wkT, const bf16* __restrict__ wvT,
    bf16* __restrict__ WcTb)
{
  __shared__ __align__(16) short As[2][128 * 32];
  __shared__ __align__(16) short Bs[2][128 * 32];
  const int t3 = blockIdx.z;
  const bf16* BT = (t3 == 0) ? wqT : (t3 == 1) ? wkT : wvT;
  const int m0 = blockIdx.y * 128, n0 = blockIdx.x * 128;
  const int tid = threadIdx.x, lane = tid & 63, w = tid >> 6;
  const int tt = lane & 15, q4 = lane >> 4;
  const int moff = (w & 1) * 64, noff = (w >> 1) * 64;
  const int r_a = tid >> 2, kc = (tid & 3) * 8;

  f32x4 acc[4][4];
#pragma unroll
  for (int i = 0; i < 4; ++i)
#pragma unroll
    for (int j = 0; j < 4; ++j) acc[i][j] = (f32x4){0.f, 0.f, 0.f, 0.f};

#define STAGE_C(k0, buf)                                                        \
  {                                                                             \
    gll16(wqkvb + (size_t)(m0 + r_a) * 2304 + t3 * 768 + (k0) + kc,             \
          &As[buf][w * 512]);                                                   \
    gll16(wqkvb + (size_t)(m0 + r_a + 64) * 2304 + t3 * 768 + (k0) + kc,        \
          &As[buf][2048 + w * 512]);                                            \
    gll16(BT + (size_t)(n0 + r_a) * 768 + (k0) + kc, &Bs[buf][w * 512]);        \
    gll16(BT + (size_t)(n0 + r_a + 64) * 768 + (k0) + kc,                       \
          &Bs[buf][2048 + w * 512]);                                            \
  }

  STAGE_C(0, 0);
  for (int it = 0; it < 24; ++it) {
    __syncthreads();
    if (it < 23) STAGE_C((it + 1) * 32, (it + 1) & 1);
    const short* as = As[it & 1];
    const short* bs = Bs[it & 1];
    short8b afr[4], bfr[4];
#pragma unroll
    for (int mt = 0; mt < 4; ++mt)
      afr[mt] = *(const short8b*)&as[(moff + mt * 16 + tt) * 32 + q4 * 8];
#pragma unroll
    for (int nt = 0; nt < 4; ++nt)
      bfr[nt] = *(const short8b*)&bs[(noff + nt * 16 + tt) * 32 + q4 * 8];
#pragma unroll
    for (int mt = 0; mt < 4; ++mt)
#pragma unroll
      for (int nt = 0; nt < 4; ++nt)
        acc[mt][nt] = __builtin_amdgcn_mfma_f32_16x16x32_bf16(afr[mt], bfr[nt], acc[mt][nt], 0, 0, 0);
  }
#undef STAGE_C

  bf16* C = WcTb + (size_t)t3 * 768 * 768;
#pragma unroll
  for (int nt = 0; nt < 4; ++nt) {
    int n = n0 + noff + nt * 16 + tt;
#pragma unroll
    for (int mt = 0; mt < 4; ++mt) {
      int mb = m0 + moff + mt * 16 + q4 * 4;
      short4b v = {f2bs(acc[mt][nt][0]), f2bs(acc[mt][nt][1]),
                   f2bs(acc[mt][nt][2]), f2bs(acc[mt][nt][3])};
      *(short4b*)&C[(size_t)n * 768 + mb] = v;
    }
  }
}

// qh/kh/vh = xb @ Wc[t] + bias, scattered to [(b*12+h)][n][d] bf16
__global__ __launch_bounds__(256) void k_proj_m(
    const bf16* __restrict__ xb, const bf16* __restrict__ WcTb,
    const float* __restrict__ bq, const float* __restrict__ bk,
    const float* __restrict__ bv,
    bf16* __restrict__ qh, bf16* __restrict__ kh, bf16* __restrict__ vh)
{
  __shared__ __align__(16) short As[2][128 * 32];
  __shared__ __align__(16) short Bs[2][128 * 32];
  const int t3 = blockIdx.z;
  const bf16* BT = WcTb + (size_t)t3 * 768 * 768;
  const float* bias = (t3 == 0) ? bq : (t3 == 1) ? bk : bv;
  bf16* dst = (t3 == 0) ? qh : (t3 == 1) ? kh : vh;
  const int m0 = blockIdx.y * 128, n0 = blockIdx.x * 128;
  const int tid = threadIdx.x, lane = tid & 63, w = tid >> 6;
  const int tt = lane & 15, q4 = lane >> 4;
  const int moff = (w & 1) * 64, noff = (w >> 1) * 64;
  const int r_a = tid >> 2, kc = (tid & 3) * 8;

  f32x4 acc[4][4];
#pragma unroll
  for (int i = 0; i < 4; ++i)
#pragma unroll
    for (int j = 0; j < 4; ++j) acc[i][j] = (f32x4){0.f, 0.f, 0.f, 0.f};

#define STAGE_P(k0, buf)                                                        \
  {                                                                             \
    gll16(xb + (size_t)(m0 + r_a) * 768 + (k0) + kc, &As[buf][w * 512]);        \
    gll16(xb + (size_t)(m0 + r_a + 64) * 768 + (k0) + kc,                       \
          &As[buf][2048 + w * 512]);                                            \
    gll16(BT + (size_t)(n0 + r_a) * 768 + (k0) + kc, &Bs[buf][w * 512]);        \
    gll16(BT + (size_t)(n0 + r_a + 64) * 768 + (k0) + kc,                       \
          &Bs[buf][2048 + w * 512]);                                            \
  }

  STAGE_P(0, 0);
  for (int it = 0; it < 24; ++it) {
    __syncthreads();
    if (it < 23) STAGE_P((it + 1) * 32, (it + 1) & 1);
    const short* as = As[it & 1];
    const short* bs = Bs[it & 1];
    short8b afr[4], bfr[4];
#pragma unroll
    for (int mt = 0; mt < 4; ++mt)
      afr[mt] = *(const short8b*)&as[(moff + mt * 16 + tt) * 32 + q4 * 8];
#pragma unroll
    for (int nt = 0; nt < 4; ++nt)
      bfr[nt] = *(const short8b*)&bs[(noff + nt * 16 + tt) * 32 + q4 * 8];
#pragma unroll
    for (int mt = 0; mt < 4; ++mt)
#pragma unroll
      for (int nt = 0; nt < 4; ++nt)
        acc[mt][nt] = __builtin_amdgcn_mfma_f32_16x16x32_bf16(afr[mt], bfr[nt], acc[mt][nt], 0, 0, 0);
  }
#undef STAGE_P

#pragma unroll
  for (int nt = 0; nt < 4; ++nt) {
    int c = n0 + noff + nt * 16 + tt;
    float bvv = bias[c];
    int h = c >> 6, d = c & 63;
#pragma unroll
    for (int mt = 0; mt < 4; ++mt) {
#pragma unroll
      for (int r = 0; r < 4; ++r) {
        int m = m0 + moff + mt * 16 + q4 * 4 + r;
        dst[(((size_t)((m >> 8) * 12 + h)) << 14) + ((m & 255) << 6) + d] =
            __float2bfloat16(acc[mt][nt][r] + bvv);
      }
    }
  }
}

// out = gather(attno) @ wo + bo (fp32 out)
__global__ __launch_bounds__(256) void k_out_m(
    const bf16* __restrict__ attno, const bf16* __restrict__ woT,
    const float* __restrict__ bo, float* __restrict__ out)
{
  __shared__ __align__(16) short As[2][128 * 32];
  __shared__ __align__(16) short Bs[2][128 * 32];
  const int m0 = blockIdx.y * 128, n0 = blockIdx.x * 128;
  const int tid = threadIdx.x, lane = tid & 63, w = tid >> 6;
  const int tt = lane & 15, q4 = lane >> 4;
  const int moff = (w & 1) * 64, noff = (w >> 1) * 64;
  const int r_a = tid >> 2, kc = (tid & 3) * 8;
  const int m_a0 = m0 + r_a, m_a1 = m0 + r_a + 64;

  f32x4 acc[4][4];
#pragma unroll
  for (int i = 0; i < 4; ++i)
#pragma unroll
    for (int j = 0; j < 4; ++j) acc[i][j] = (f32x4){0.f, 0.f, 0.f, 0.f};

#define STAGE_O(k0, buf)                                                        \
  {                                                                             \
    int k = (k0) + kc;                                                          \
    gll16(attno + (((size_t)((m_a0 >> 8) * 12 + (k >> 6))) << 14) +             \
              ((m_a0 & 255) << 6) + (k & 63),                                   \
          &As[buf][w * 512]);                                                   \
    gll16(attno + (((size_t)((m_a1 >> 8) * 12 + (k >> 6))) << 14) +             \
              ((m_a1 & 255) << 6) + (k & 63),                                   \
          &As[buf][2048 + w * 512]);                                            \
    gll16(woT + (size_t)(n0 + r_a) * 768 + k, &Bs[buf][w * 512]);               \
    gll16(woT + (size_t)(n0 + r_a + 64) * 768 + k, &Bs[buf][2048 + w * 512]);   \
  }

  STAGE_O(0, 0);
  for (int it = 0; it < 24; ++it) {
    __syncthreads();
    if (it < 23) STAGE_O((it + 1) * 32, (it + 1) & 1);
    const short* as = As[it & 1];
    const short* bs = Bs[it & 1];
    short8b afr[4], bfr[4];
#pragma unroll
    for (int mt = 0; mt < 4; ++mt)
      afr[mt] = *(const short8b*)&as[(moff + mt * 16 + tt) * 32 + q4 * 8];
#pragma unroll
    for (int nt = 0; nt < 4; ++nt)
      bfr[nt] = *(const short8b*)&bs[(noff + nt * 16 + tt) * 32 + q4 * 8];
#pragma unroll
    for (int mt = 0; mt < 4; ++mt)
#pragma unroll
      for (int nt = 0; nt < 4; ++nt)
        acc[mt][nt] = __builtin_amdgcn_mfma_f32_16x16x32_bf16(afr[mt], bfr[nt], acc[mt][nt], 0, 0, 0);
  }
#undef STAGE_O

#pragma unroll
  for (int nt = 0; nt < 4; ++nt) {
    int c = n0 + noff + nt * 16 + tt;
    float bvv = bo[c];
#pragma unroll
    for (int mt = 0; mt < 4; ++mt)
#pragma unroll
      for (int r = 0; r < 4; ++r) {
        int m = m0 + moff + mt * 16 + q4 * 4 + r;
        out[(size_t)m * 768 + c] = acc[mt][nt][r] + bvv;
      }
  }
}

// ---------------------------------------------------------------------------
// Parallel integral image: block = (bh, mat), 1024 thr, LDS two-pass scan.
// ---------------------------------------------------------------------------
__global__ __launch_bounds__(1024) void k_integral_p(
    const bf16* __restrict__ kh, const bf16* __restrict__ vh,
    float* __restrict__ Ik, float* __restrict__ Iv)
{
  __shared__ float sat[17 * 17 * 64];
  int bh = blockIdx.x >> 1;
  bool isv = blockIdx.x & 1;
  const bf16* src = (isv ? vh : kh) + ((size_t)bh << 14);
  float* dst = (isv ? Iv : Ik) + (size_t)bh * 18496;
  int tid = threadIdx.x;
  int d = tid & 63;
  int row = tid >> 6;
  {
    float run = 0.f;
    sat[((row + 1) * 17) * 64 + d] = 0.f;
#pragma unroll
    for (int xx = 0; xx < 16; ++xx) {
      run += b2f(src[(row * 16 + xx) * 64 + d]);
      sat[((row + 1) * 17 + (xx + 1)) * 64 + d] = run;
    }
    if (row == 0) {
#pragma unroll
      for (int xx = 0; xx < 17; ++xx) sat[xx * 64 + d] = 0.f;
    }
  }
  __syncthreads();
  {
    int x = row + 1;
    float run = 0.f;
#pragma unroll
    for (int y = 1; y <= 16; ++y) {
      run += sat[(y * 17 + x) * 64 + d];
      sat[(y * 17 + x) * 64 + d] = run;
    }
  }
  __syncthreads();
  for (int i = tid; i < 18496; i += 1024) dst[i] = sat[i];
}

// ---------------------------------------------------------------------------
// MFMA flash attention with FREE P-transpose; AREA-SPLIT 4x for occupancy:
// grid (192 bh, 4 chunks); each block does 8 of the 32 area-tiles (512 areas)
// for all 256 queries. Softmax has no running max (p = exp(s)), so partial
// (O, l) combine ADDITIVELY -> fire-and-forget f32 atomicAdd into Oacc/lacc
// (zeroed via memset), normalized by k_norm. 768 blocks -> 2 resident
// blocks/CU = 32 waves (was: 192 blocks, 64 CUs idle, 16 waves/CU).
// Chunk-blocks of one bh are ids 192 apart (192%8==0 -> same XCD, share
// Ik/Iv in that XCD's L2).
//   QK at-MFMA A row (lane t) = (at>>1)*32 + (t&12)*2 + (at&1)*4 + (t&3)
//   => lane (t,q4) reg r = P[area=(at>>1)*32+q4*8+(at&1)*4+r][query=t]
//   => apv[chunk=at>>1] shorts j=(at&1)*4+r  (A[m=t][k=q4*8+j], k==area) ✓
// aK stride 80 keeps permuted b128 reads bank-balanced ((2row+q4) mod 8 unif).
// ---------------------------------------------------------------------------
__global__ __launch_bounds__(1024) void k_attn_m(
    const bf16* __restrict__ qh, const float* __restrict__ Ik,
    const float* __restrict__ Iv, const int4* __restrict__ rectG,
    const float* __restrict__ invG, float* __restrict__ Oacc,
    float* __restrict__ lacc)
{
  __shared__ __align__(16) short aK2[2][64 * 80];
  __shared__ __align__(16) short aVt2[2][64 * 72];

  const int tid = threadIdx.x;
  const int lane = tid & 63;
  const int w = tid >> 6;
  const int t = lane & 15;
  const int q4 = lane >> 4;
  const int bh = blockIdx.x;
  const int it0 = blockIdx.y * 8;      // this chunk: tiles [it0, it0+8)
  const int rbase = (t & 12) * 2 + (t & 3);

  const float* Ikb = Ik + (size_t)bh * 18496;
  const float* Ivb = Iv + (size_t)bh * 18496;
  const bf16* qbase = qh + ((size_t)bh << 14);

  short8b qf0 = *(const short8b*)(qbase + (w * 16 + t) * 64 + q4 * 8);
  short8b qf1 = *(const short8b*)(qbase + (w * 16 + t) * 64 + 32 + q4 * 8);

  f32x4 O[4];
#pragma unroll
  for (int i = 0; i < 4; ++i) O[i] = (f32x4){0.f, 0.f, 0.f, 0.f};
  float l = 0.f;

  // stage tile it0 (it0 is even -> buffer 0, matching aK2[it & 1] below)
  {
    short* aK = aK2[0];
    short* aVt = aVt2[0];
    short vp[4];
#pragma unroll
    for (int i = 0; i < 4; ++i) {
      int j = w * 4 + i;
      int g = it0 * 64 + j;
      int4 rc = rectG[g];
      float iv = invG[g];
      float kc = Ikb[rc.w + lane] - Ikb[rc.y + lane] - Ikb[rc.z + lane] + Ikb[rc.x + lane];
      float vc = Ivb[rc.w + lane] - Ivb[rc.y + lane] - Ivb[rc.z + lane] + Ivb[rc.x + lane];
      aK[j * 80 + lane] = f2bs(kc * iv);
      vp[i] = f2bs(vc);
    }
    *(short4b*)&aVt[lane * 72 + w * 4] = (short4b){vp[0], vp[1], vp[2], vp[3]};
  }

  float kcr[4], vcr[4], ivr[4];
  for (int it = it0; it < it0 + 8; ++it) {
    if (it + 1 < it0 + 8) {
      int t0n = (it + 1) * 64;
#pragma unroll
      for (int i = 0; i < 4; ++i) {
        int j = t0n + w * 4 + i;
        int4 rc = rectG[j];
        ivr[i] = invG[j];
        kcr[i] = Ikb[rc.w + lane] - Ikb[rc.y + lane] - Ikb[rc.z + lane] + Ikb[rc.x + lane];
        vcr[i] = Ivb[rc.w + lane] - Ivb[rc.y + lane] - Ivb[rc.z + lane] + Ivb[rc.x + lane];
      }
    }
    __syncthreads();
    const short* aK = aK2[it & 1];
    const short* aVt = aVt2[it & 1];
    if (it + 1 < it0 + 8) {
      short* aKn = aK2[(it + 1) & 1];
      short* aVtn = aVt2[(it + 1) & 1];
      short vp[4];
#pragma unroll
      for (int i = 0; i < 4; ++i) {
        aKn[(w * 4 + i) * 80 + lane] = f2bs(kcr[i] * ivr[i]);
        vp[i] = f2bs(vcr[i]);
      }
      *(short4b*)&aVtn[lane * 72 + w * 4] = (short4b){vp[0], vp[1], vp[2], vp[3]};
    }

    const int t0 = it * 64;
    const bool edge = (t0 + 64 > NAREA);
    union { short8b v; unsigned u[4]; } apv[2];
#pragma unroll
    for (int at = 0; at < 4; ++at) {
      int row = rbase + (at & 1) * 4 + (at >> 1) * 32;
      short8b af0 = *(const short8b*)&aK[row * 80 + q4 * 8];
      short8b af1 = *(const short8b*)&aK[row * 80 + 32 + q4 * 8];
      f32x4 s = (f32x4){0.f, 0.f, 0.f, 0.f};
      s = __builtin_amdgcn_mfma_f32_16x16x32_bf16(af0, qf0, s, 0, 0, 0);
      s = __builtin_amdgcn_mfma_f32_16x16x32_bf16(af1, qf1, s, 0, 0, 0);
      int abase = t0 + (at >> 1) * 32 + q4 * 8 + (at & 1) * 4;
      float p[4];
#pragma unroll
      for (int r = 0; r < 4; ++r) {
        p[r] = __expf(s[r]);
        if (edge && (abase + r >= NAREA)) p[r] = 0.f;
      }
      l += (p[0] + p[1]) + (p[2] + p[3]);
      unsigned lo = ((unsigned)(unsigned short)f2bs(p[1]) << 16) |
                    (unsigned short)f2bs(p[0]);
      unsigned hi = ((unsigned)(unsigned short)f2bs(p[3]) << 16) |
                    (unsigned short)f2bs(p[2]);
      apv[at >> 1].u[(at & 1) * 2 + 0] = lo;
      apv[at >> 1].u[(at & 1) * 2 + 1] = hi;
    }
#pragma unroll
    for (int nt = 0; nt < 4; ++nt) {
      short8b vf0 = *(const short8b*)&aVt[(nt * 16 + t) * 72 + q4 * 8];
      short8b vf1 = *(const short8b*)&aVt[(nt * 16 + t) * 72 + 32 + q4 * 8];
      O[nt] = __builtin_amdgcn_mfma_f32_16x16x32_bf16(apv[0].v, vf0, O[nt], 0, 0, 0);
      O[nt] = __builtin_amdgcn_mfma_f32_16x16x32_bf16(apv[1].v, vf1, O[nt], 0, 0, 0);
    }
  }

  l += __shfl_xor(l, 16, 64);
  l += __shfl_xor(l, 32, 64);

  // additive partial combine: chunk contributions sum exactly (no max shift)
  if (q4 == 0) atomicAdd(lacc + (bh << 8) + w * 16 + t, l);
  float* Ob = Oacc + ((size_t)bh << 14);
#pragma unroll
  for (int nt = 0; nt < 4; ++nt)
#pragma unroll
    for (int r = 0; r < 4; ++r)
      atomicAdd(Ob + (w * 16 + q4 * 4 + r) * 64 + nt * 16 + t, O[nt][r]);
}

// ---------------------------------------------------------------------------
// Normalize accumulated O by accumulated l, cast to bf16 attno layout.
// 3072 blocks x 256 thr x 4 floats = 192*256*64.
// ---------------------------------------------------------------------------
__global__ __launch_bounds__(256) void k_norm(
    const float* __restrict__ Oacc, const float* __restrict__ lacc,
    bf16* __restrict__ attno)
{
  int i = (blockIdx.x * 256 + threadIdx.x) * 4;
  f32x4 o = *(const f32x4*)(Oacc + i);
  float invl = 1.0f / lacc[i >> 6];
  short4b s = {f2bs(o[0] * invl), f2bs(o[1] * invl),
               f2bs(o[2] * invl), f2bs(o[3] * invl)};
  *(short4b*)(attno + i) = s;
}

extern "C" void kernel_launch(void* const* d_in, const int* in_sizes, int n_in,
                              void* d_out, int out_size, void* d_ws, size_t ws_size,
                              hipStream_t stream) {
  const float* x    = (const float*)d_in[0];
  const float* wqkv = (const float*)d_in[1];
  const float* wq   = (const float*)d_in[2];
  const float* bq   = (const float*)d_in[3];
  const float* wk   = (const float*)d_in[4];
  const float* bk   = (const float*)d_in[5];
  const float* wv   = (const float*)d_in[6];
  const float* bv   = (const float*)d_in[7];
  const float* wo   = (const float*)d_in[8];
  const float* bo   = (const float*)d_in[9];
  float* out = (float*)d_out;

  char* ws = (char*)d_ws;
  char* ob = (char*)d_out;
  const size_t WC_B = 7077888;   // zone A size
  const size_t QH_B = 6291456;   // bf16 [192][256][64]

  // d_out as scratch: xb + WcTb (dead after k_proj_m), then Oacc (f32 attn
  // accumulator, 192*256*64*4 = 12582912 = out_size), consumed by k_norm
  // before k_out_m finally writes out.
  bf16* xb    = (bf16*)ob;                  // [0, 6291456)
  bf16* WcTb  = (bf16*)(ob + QH_B);         // [6291456, 9830400)
  float* Oacc = (float*)ob;                 // full 12582912 B
  // ws zone A: attno [0,6291456), rectG/invG after, then lacc
  bf16* attno = (bf16*)ws;
  int4*  rectG = (int4*)(ws + QH_B);             // [6291456, 6324224)
  float* invG  = (float*)(ws + QH_B + 32768);    // [6324224, 6332416)
  float* lacc  = (float*)(ws + QH_B + 40960);    // [6332416, 6529024) < WC_B
  // qh/kh/vh
  bf16* qh = (bf16*)(ws + WC_B);
  bf16* kh = (bf16*)(ws + WC_B + QH_B);
  bf16* vh = (bf16*)(ws + WC_B + 2 * QH_B);
  // pre-k_proj aliases into (not-yet-written) qh/kh region
  bf16* wqkvb = (bf16*)(ws + WC_B);
  bf16* wqT   = (bf16*)(ws + WC_B + 3538944);
  bf16* wkT   = (bf16*)(ws + WC_B + 4718592);
  bf16* wvT   = (bf16*)(ws + WC_B + 5898240);
  // SAT; woT aliases dead Ik after attn
  float* Ik = (float*)(ws + WC_B + 3 * QH_B);
  float* Iv = Ik + 3551232;                      // total 54,362,112 (known fit)
  bf16* woT = (bf16*)(ws + WC_B + 3 * QH_B);

  k_prep<<<dim3(6536), 256, 0, stream>>>(x, wqkv, wq, wk, wv, xb, wqkvb,
                                         wqT, wkT, wvT, rectG, invG);
  k_combine_m<<<dim3(6, 6, 3), 256, 0, stream>>>(wqkvb, wqT, wkT, wvT, WcTb);
  k_proj_m<<<dim3(6, 32, 3), 256, 0, stream>>>(xb, WcTb, bq, bk, bv, qh, kh, vh);
  // xb/WcTb dead now -> zero d_out for Oacc accumulation; zero lacc too
  hipMemsetAsync(Oacc, 0, 12582912, stream);
  hipMemsetAsync(lacc, 0, 196608, stream);
  k_integral_p<<<dim3(384), 1024, 0, stream>>>(kh, vh, Ik, Iv);
  k_attn_m<<<dim3(192, 4), 1024, 0, stream>>>(qh, Ik, Iv, rectG, invG, Oacc, lacc);
  k_norm<<<dim3(3072), 256, 0, stream>>>(Oacc, lacc, attno);
  k_tcast1<<<dim3(24, 24), 256, 0, stream>>>(wo, woT);
  k_out_m<<<dim3(6, 32), 256, 0, stream>>>(attno, woT, bo, out);
}